// Round 12
// baseline (257.526 us; speedup 1.0000x reference)
//
#include <hip/hip_runtime.h>
#include <hip/hip_bf16.h>

// ---------------------------------------------------------------------------
// 4-layer GCN forward (PyG gcn_norm: add self-loops, D^-1/2 A D^-1/2)
// h stored bf16. Hidden layers (reassociated): h' = relu((A·h)·W + b),
// fused gather + MFMA (32 nodes/block, sequential node order).
// Gather loop unrolled x4 (8 outstanding uint4 loads/lane) with
// launch_bounds(256,6) so the staging registers fit without spill.
// Layer 2 fuses the W3 projection (h3 never hits global memory).
// Final: out = A·hw3 + b3 (bf16 gather, 80B rows).
// ---------------------------------------------------------------------------

#define F_DIM 128

#define SCAN_T 256
#define SCAN_I 8
#define SCAN_CHUNK (SCAN_T * SCAN_I)   // 2048 items per block

typedef __attribute__((ext_vector_type(8))) short short8;
typedef __attribute__((ext_vector_type(4))) float f32x4;

__device__ __forceinline__ unsigned short f2bf_rne(float f) {
    unsigned int u = __float_as_uint(f);
    unsigned int r = (u + 0x7fffu + ((u >> 16) & 1u)) >> 16;
    return (unsigned short)r;
}

__global__ void count_dst_kernel(const int* __restrict__ dst, int* __restrict__ count, int E) {
    int e = blockIdx.x * blockDim.x + threadIdx.x;
    if (e < E) atomicAdd(&count[dst[e]], 1);
}

// ---- two-level scan of (count[i]+1) ---------------------------------------
__global__ __launch_bounds__(SCAN_T) void scan_partial_kernel(const int* __restrict__ count,
                                                              int* __restrict__ blocksum, int n) {
    int b = blockIdx.x, t = threadIdx.x;
    int base = b * SCAN_CHUNK + t * SCAN_I;
    int s = 0;
#pragma unroll
    for (int j = 0; j < SCAN_I; ++j) {
        int i = base + j;
        if (i < n) s += count[i] + 1;
    }
    __shared__ int red[SCAN_T];
    red[t] = s;
    __syncthreads();
    for (int off = SCAN_T / 2; off > 0; off >>= 1) {
        if (t < off) red[t] += red[t + off];
        __syncthreads();
    }
    if (t == 0) blocksum[b] = red[0];
}

__global__ __launch_bounds__(1024) void scan_sums_kernel(const int* __restrict__ blocksum,
                                                         int* __restrict__ blockoff, int nb) {
    __shared__ int sums[1024];
    int t = threadIdx.x;
    sums[t] = (t < nb) ? blocksum[t] : 0;
    __syncthreads();
    for (int off = 1; off < 1024; off <<= 1) {
        int v = (t >= off) ? sums[t - off] : 0;
        __syncthreads();
        sums[t] += v;
        __syncthreads();
    }
    if (t < nb) blockoff[t] = (t == 0) ? 0 : sums[t - 1];
    if (t == 0) blockoff[nb] = sums[nb - 1];
}

// scan_write + dinv + self-loop fill fused
__global__ __launch_bounds__(SCAN_T) void scan_write_fused_kernel(const int* __restrict__ count,
                                                                  const int* __restrict__ blockoff,
                                                                  int* __restrict__ rowptr,
                                                                  int* __restrict__ writepos,
                                                                  float* __restrict__ dinv,
                                                                  int* __restrict__ col,
                                                                  float* __restrict__ val,
                                                                  int n, int nb) {
    int b = blockIdx.x, t = threadIdx.x;
    int base = b * SCAN_CHUNK + t * SCAN_I;
    int c[SCAN_I];
    int s = 0;
#pragma unroll
    for (int j = 0; j < SCAN_I; ++j) {
        int i = base + j;
        c[j] = (i < n) ? count[i] + 1 : 0;
        s += c[j];
    }
    __shared__ int sums[SCAN_T];
    sums[t] = s;
    __syncthreads();
    for (int off = 1; off < SCAN_T; off <<= 1) {
        int v = (t >= off) ? sums[t - off] : 0;
        __syncthreads();
        sums[t] += v;
        __syncthreads();
    }
    int offset = blockoff[b] + ((t == 0) ? 0 : sums[t - 1]);
#pragma unroll
    for (int j = 0; j < SCAN_I; ++j) {
        int i = base + j;
        if (i < n) {
            rowptr[i] = offset;
            float d = rsqrtf((float)c[j]);
            dinv[i] = d;
            col[offset] = i;
            val[offset] = d * d;
            writepos[i] = offset + 1;
            offset += c[j];
        }
    }
    if (b == 0 && t == 0) rowptr[n] = blockoff[nb];
}

__global__ void fill_edges_kernel(const int* __restrict__ src, const int* __restrict__ dst,
                                  int* __restrict__ writepos, int* __restrict__ col,
                                  float* __restrict__ val, const float* __restrict__ dinv, int E) {
    int e = blockIdx.x * blockDim.x + threadIdx.x;
    if (e < E) {
        int s = src[e], d = dst[e];
        int p = atomicAdd(&writepos[d], 1);
        col[p] = s;
        val[p] = dinv[s] * dinv[d];
    }
}

// ---- f32 -> bf16 conversion (x input), 8 elems/thread ---------------------
__global__ __launch_bounds__(256) void cvt_bf16_kernel(const float* __restrict__ in,
                                                       unsigned short* __restrict__ out,
                                                       long nChunks) {
    long idx = (long)blockIdx.x * 256 + threadIdx.x;
    if (idx >= nChunks) return;
    const float4* in4 = (const float4*)in;
    float4 a = in4[idx * 2];
    float4 b = in4[idx * 2 + 1];
    uint4 o;
    o.x = (unsigned)f2bf_rne(a.x) | ((unsigned)f2bf_rne(a.y) << 16);
    o.y = (unsigned)f2bf_rne(a.z) | ((unsigned)f2bf_rne(a.w) << 16);
    o.z = (unsigned)f2bf_rne(b.x) | ((unsigned)f2bf_rne(b.y) << 16);
    o.w = (unsigned)f2bf_rne(b.z) | ((unsigned)f2bf_rne(b.w) << 16);
    ((uint4*)out)[idx] = o;
}

// ---- ALL weight conversions in one kernel ---------------------------------
// t in [0, 3*16384): WT{0,1,2}[c][k] = bf16(W{0,1,2}[k][c])
// t in [3*16384, +48*128): WT3[c][k] = bf16(W3[k][c]) (c>=40 -> 0)
__global__ __launch_bounds__(256) void cvt_weights_kernel(const float* __restrict__ W0,
                                                          const float* __restrict__ W1,
                                                          const float* __restrict__ W2,
                                                          const float* __restrict__ W3,
                                                          unsigned short* __restrict__ WT0,
                                                          unsigned short* __restrict__ WT1,
                                                          unsigned short* __restrict__ WT2,
                                                          unsigned short* __restrict__ WT3) {
    int t = blockIdx.x * 256 + threadIdx.x;
    if (t < 3 * 16384) {
        int w = t >> 14, i = t & 16383;
        int k = i >> 7, c = i & 127;
        const float* W = (w == 0) ? W0 : (w == 1) ? W1 : W2;
        unsigned short* WT = (w == 0) ? WT0 : (w == 1) ? WT1 : WT2;
        WT[(size_t)c * 128 + k] = f2bf_rne(W[(size_t)k * 128 + c]);
    } else {
        int i = t - 3 * 16384;
        if (i < 48 * 128) {
            int c = i >> 7, k = i & 127;
            WT3[(size_t)c * 128 + k] = (c < 40) ? f2bf_rne(W3[(size_t)k * 40 + c])
                                                : (unsigned short)0;
        }
    }
}

// unpack-accumulate: acc[0..7] += v * bf16x8(u)
__device__ __forceinline__ void acc8_bf16(float* acc, uint4 u, float v) {
    unsigned w[4] = {u.x, u.y, u.z, u.w};
#pragma unroll
    for (int i = 0; i < 4; ++i) {
        float lo = __uint_as_float(w[i] << 16);
        float hi = __uint_as_float(w[i] & 0xffff0000u);
        acc[2 * i] += v * lo;
        acc[2 * i + 1] += v * hi;
    }
}

// ---- phase-1 gather, edge loop unrolled x4 --------------------------------
__device__ __forceinline__ void gather_phase1(const int* __restrict__ rowptr,
                                              const int* __restrict__ col,
                                              const float* __restrict__ val,
                                              const uint4* __restrict__ H16,
                                              unsigned short (*aggb)[136], int n) {
    int m = threadIdx.x >> 3;
    int p = threadIdx.x & 7;
    int node = blockIdx.x * 32 + m;
    float acc[16];
#pragma unroll
    for (int q = 0; q < 16; ++q) acc[q] = 0.f;
    if (node < n) {
        int s = rowptr[node], e = rowptr[node + 1];
        int j = s;
        // 4-edge straight-line body: 8 uint4 loads issued before accumulation
        for (; j + 3 < e; j += 4) {
            int c0 = col[j], c1 = col[j + 1], c2 = col[j + 2], c3 = col[j + 3];
            float v0 = val[j], v1 = val[j + 1], v2 = val[j + 2], v3 = val[j + 3];
            const uint4* r0 = H16 + (size_t)c0 * 16 + p;
            const uint4* r1 = H16 + (size_t)c1 * 16 + p;
            const uint4* r2 = H16 + (size_t)c2 * 16 + p;
            const uint4* r3 = H16 + (size_t)c3 * 16 + p;
            uint4 a0 = r0[0], a1 = r0[8];
            uint4 b0 = r1[0], b1 = r1[8];
            uint4 g0 = r2[0], g1 = r2[8];
            uint4 d0 = r3[0], d1 = r3[8];
            acc8_bf16(acc + 0, a0, v0);
            acc8_bf16(acc + 8, a1, v0);
            acc8_bf16(acc + 0, b0, v1);
            acc8_bf16(acc + 8, b1, v1);
            acc8_bf16(acc + 0, g0, v2);
            acc8_bf16(acc + 8, g1, v2);
            acc8_bf16(acc + 0, d0, v3);
            acc8_bf16(acc + 8, d1, v3);
        }
        for (; j + 1 < e; j += 2) {
            int c0 = col[j], c1 = col[j + 1];
            float v0 = val[j], v1 = val[j + 1];
            const uint4* r0 = H16 + (size_t)c0 * 16 + p;
            const uint4* r1 = H16 + (size_t)c1 * 16 + p;
            uint4 a0 = r0[0], a1 = r0[8];
            uint4 b0 = r1[0], b1 = r1[8];
            acc8_bf16(acc + 0, a0, v0);
            acc8_bf16(acc + 8, a1, v0);
            acc8_bf16(acc + 0, b0, v1);
            acc8_bf16(acc + 8, b1, v1);
        }
        if (j < e) {
            int c0 = col[j];
            float v0 = val[j];
            const uint4* r0 = H16 + (size_t)c0 * 16 + p;
            uint4 a0 = r0[0], a1 = r0[8];
            acc8_bf16(acc + 0, a0, v0);
            acc8_bf16(acc + 8, a1, v0);
        }
    }
    short8 s0, s1;
#pragma unroll
    for (int q = 0; q < 8; ++q) s0[q] = (short)f2bf_rne(acc[q]);
#pragma unroll
    for (int q = 0; q < 8; ++q) s1[q] = (short)f2bf_rne(acc[8 + q]);
    *(short8*)&aggb[m][8 * p] = s0;
    *(short8*)&aggb[m][64 + 8 * p] = s1;
}

// ---- fused hidden layer (bf16 in/out, MFMA phase 2) -----------------------
__global__ __launch_bounds__(256, 6) void fused_layer_mfma(const int* __restrict__ rowptr,
                                                           const int* __restrict__ col,
                                                           const float* __restrict__ val,
                                                           const unsigned short* __restrict__ Hin,
                                                           const unsigned short* __restrict__ WT,
                                                           const float* __restrict__ bias,
                                                           unsigned short* __restrict__ Hout,
                                                           int n) {
    __shared__ unsigned short aggb[32][136];
    gather_phase1(rowptr, col, val, (const uint4*)Hin, aggb, n);
    __syncthreads();

    int lane = threadIdx.x & 63;
    int wv = threadIdx.x >> 6;
    int l15 = lane & 15;
    int lg = lane >> 4;

    f32x4 a00 = {0.f, 0.f, 0.f, 0.f}, a01 = a00, a10 = a00, a11 = a00;

#pragma unroll
    for (int kc = 0; kc < 4; ++kc) {
        int ko = kc * 32 + lg * 8;
        short8 fa0 = *(const short8*)&aggb[l15][ko];
        short8 fa1 = *(const short8*)&aggb[l15 + 16][ko];
        short8 fb0 = *(const short8*)&WT[(size_t)(wv * 32 + l15) * 128 + ko];
        short8 fb1 = *(const short8*)&WT[(size_t)(wv * 32 + 16 + l15) * 128 + ko];
        a00 = __builtin_amdgcn_mfma_f32_16x16x32_bf16(fa0, fb0, a00, 0, 0, 0);
        a01 = __builtin_amdgcn_mfma_f32_16x16x32_bf16(fa0, fb1, a01, 0, 0, 0);
        a10 = __builtin_amdgcn_mfma_f32_16x16x32_bf16(fa1, fb0, a10, 0, 0, 0);
        a11 = __builtin_amdgcn_mfma_f32_16x16x32_bf16(fa1, fb1, a11, 0, 0, 0);
    }

    int base = blockIdx.x * 32;
#pragma unroll
    for (int nt = 0; nt < 2; ++nt) {
        int c = wv * 32 + nt * 16 + l15;
        float bv = bias[c];
#pragma unroll
        for (int mt = 0; mt < 2; ++mt) {
            f32x4 acc = (mt == 0) ? (nt == 0 ? a00 : a01) : (nt == 0 ? a10 : a11);
#pragma unroll
            for (int r = 0; r < 4; ++r) {
                int node = base + mt * 16 + lg * 4 + r;
                if (node < n) {
                    float o = fmaxf(acc[r] + bv, 0.f);
                    Hout[(size_t)node * 128 + c] = f2bf_rne(o);
                }
            }
        }
    }
}

// ---- fused layer 2 + W3 projection ----------------------------------------
__global__ __launch_bounds__(256, 6) void fused_layer_mfma_w3(const int* __restrict__ rowptr,
                                                              const int* __restrict__ col,
                                                              const float* __restrict__ val,
                                                              const unsigned short* __restrict__ Hin,
                                                              const unsigned short* __restrict__ WT,
                                                              const float* __restrict__ bias,
                                                              const unsigned short* __restrict__ WT3,
                                                              unsigned short* __restrict__ hw3,
                                                              int n) {
    __shared__ unsigned short aggb[32][136];
    gather_phase1(rowptr, col, val, (const uint4*)Hin, aggb, n);
    __syncthreads();

    int lane = threadIdx.x & 63;
    int wv = threadIdx.x >> 6;
    int l15 = lane & 15;
    int lg = lane >> 4;

    f32x4 a00 = {0.f, 0.f, 0.f, 0.f}, a01 = a00, a10 = a00, a11 = a00;

#pragma unroll
    for (int kc = 0; kc < 4; ++kc) {
        int ko = kc * 32 + lg * 8;
        short8 fa0 = *(const short8*)&aggb[l15][ko];
        short8 fa1 = *(const short8*)&aggb[l15 + 16][ko];
        short8 fb0 = *(const short8*)&WT[(size_t)(wv * 32 + l15) * 128 + ko];
        short8 fb1 = *(const short8*)&WT[(size_t)(wv * 32 + 16 + l15) * 128 + ko];
        a00 = __builtin_amdgcn_mfma_f32_16x16x32_bf16(fa0, fb0, a00, 0, 0, 0);
        a01 = __builtin_amdgcn_mfma_f32_16x16x32_bf16(fa0, fb1, a01, 0, 0, 0);
        a10 = __builtin_amdgcn_mfma_f32_16x16x32_bf16(fa1, fb0, a10, 0, 0, 0);
        a11 = __builtin_amdgcn_mfma_f32_16x16x32_bf16(fa1, fb1, a11, 0, 0, 0);
    }

    __syncthreads();
#pragma unroll
    for (int nt = 0; nt < 2; ++nt) {
        int c = wv * 32 + nt * 16 + l15;
        float bv = bias[c];
#pragma unroll
        for (int mt = 0; mt < 2; ++mt) {
            f32x4 acc = (mt == 0) ? (nt == 0 ? a00 : a01) : (nt == 0 ? a10 : a11);
#pragma unroll
            for (int r = 0; r < 4; ++r) {
                int row = mt * 16 + lg * 4 + r;
                aggb[row][c] = f2bf_rne(fmaxf(acc[r] + bv, 0.f));
            }
        }
    }
    __syncthreads();

    if (wv < 3) {
        f32x4 c0 = {0.f, 0.f, 0.f, 0.f}, c1 = c0;
#pragma unroll
        for (int kc = 0; kc < 4; ++kc) {
            int ko = kc * 32 + lg * 8;
            short8 fa0 = *(const short8*)&aggb[l15][ko];
            short8 fa1 = *(const short8*)&aggb[l15 + 16][ko];
            short8 fb = *(const short8*)&WT3[(size_t)(wv * 16 + l15) * 128 + ko];
            c0 = __builtin_amdgcn_mfma_f32_16x16x32_bf16(fa0, fb, c0, 0, 0, 0);
            c1 = __builtin_amdgcn_mfma_f32_16x16x32_bf16(fa1, fb, c1, 0, 0, 0);
        }
        int ccol = wv * 16 + l15;
        if (ccol < 40) {
            int base = blockIdx.x * 32;
#pragma unroll
            for (int mt = 0; mt < 2; ++mt) {
                f32x4 acc = (mt == 0) ? c0 : c1;
#pragma unroll
                for (int r = 0; r < 4; ++r) {
                    int node = base + mt * 16 + lg * 4 + r;
                    if (node < n) hw3[(size_t)node * 40 + ccol] = f2bf_rne(acc[r]);
                }
            }
        }
    }
}

// ---- gather40: out[dst] = sum val * hw3_bf16[src] + b3, 40 feats ----------
// unrolled x2; block 256, 32 nodes/block, 8 thr/node
__global__ __launch_bounds__(256, 8) void gather40_bf16_kernel(const int* __restrict__ rowptr,
                                                               const int* __restrict__ col,
                                                               const float* __restrict__ val,
                                                               const unsigned short* __restrict__ hw3,
                                                               const float* __restrict__ bias,
                                                               float* __restrict__ out, int n) {
    int m = threadIdx.x >> 3;
    int p = threadIdx.x & 7;
    int node = blockIdx.x * 32 + m;
    if (node >= n) return;

    float a0x = 0.f, a0y = 0.f, a0z = 0.f, a0w = 0.f;
    float a1x = 0.f, a1y = 0.f, a1z = 0.f, a1w = 0.f;

    int s = rowptr[node], e = rowptr[node + 1];
    int j = s;
    for (; j + 1 < e; j += 2) {
        int c0 = col[j], c1 = col[j + 1];
        float v0 = val[j], v1 = val[j + 1];
        const uint2* r0 = (const uint2*)(hw3 + (size_t)c0 * 40);
        const uint2* r1 = (const uint2*)(hw3 + (size_t)c1 * 40);
        uint2 u0 = r0[p], u1 = r1[p];
        a0x += v0 * __uint_as_float(u0.x << 16) + v1 * __uint_as_float(u1.x << 16);
        a0y += v0 * __uint_as_float(u0.x & 0xffff0000u) + v1 * __uint_as_float(u1.x & 0xffff0000u);
        a0z += v0 * __uint_as_float(u0.y << 16) + v1 * __uint_as_float(u1.y << 16);
        a0w += v0 * __uint_as_float(u0.y & 0xffff0000u) + v1 * __uint_as_float(u1.y & 0xffff0000u);
        if (p < 2) {
            uint2 w0 = r0[8 + p], w1 = r1[8 + p];
            a1x += v0 * __uint_as_float(w0.x << 16) + v1 * __uint_as_float(w1.x << 16);
            a1y += v0 * __uint_as_float(w0.x & 0xffff0000u) + v1 * __uint_as_float(w1.x & 0xffff0000u);
            a1z += v0 * __uint_as_float(w0.y << 16) + v1 * __uint_as_float(w1.y << 16);
            a1w += v0 * __uint_as_float(w0.y & 0xffff0000u) + v1 * __uint_as_float(w1.y & 0xffff0000u);
        }
    }
    if (j < e) {
        int c0 = col[j];
        float v0 = val[j];
        const uint2* r0 = (const uint2*)(hw3 + (size_t)c0 * 40);
        uint2 u = r0[p];
        a0x += v0 * __uint_as_float(u.x << 16);
        a0y += v0 * __uint_as_float(u.x & 0xffff0000u);
        a0z += v0 * __uint_as_float(u.y << 16);
        a0w += v0 * __uint_as_float(u.y & 0xffff0000u);
        if (p < 2) {
            uint2 w = r0[8 + p];
            a1x += v0 * __uint_as_float(w.x << 16);
            a1y += v0 * __uint_as_float(w.x & 0xffff0000u);
            a1z += v0 * __uint_as_float(w.y << 16);
            a1w += v0 * __uint_as_float(w.y & 0xffff0000u);
        }
    }

    const float4* bi = (const float4*)bias;
    float4 bv = bi[p];
    float4 o0;
    o0.x = a0x + bv.x; o0.y = a0y + bv.y;
    o0.z = a0z + bv.z; o0.w = a0w + bv.w;
    ((float4*)(out + (size_t)node * 40))[p] = o0;
    if (p < 2) {
        float4 bw = bi[8 + p];
        float4 o1;
        o1.x = a1x + bw.x; o1.y = a1y + bw.y;
        o1.z = a1z + bw.z; o1.w = a1w + bw.w;
        ((float4*)(out + (size_t)node * 40))[8 + p] = o1;
    }
}

extern "C" void kernel_launch(void* const* d_in, const int* in_sizes, int n_in,
                              void* d_out, int out_size, void* d_ws, size_t ws_size,
                              hipStream_t stream) {
    const float* x = (const float*)d_in[0];
    const int* edge_index = (const int*)d_in[1];
    const float* W0 = (const float*)d_in[2];
    const float* b0 = (const float*)d_in[3];
    const float* W1 = (const float*)d_in[4];
    const float* b1 = (const float*)d_in[5];
    const float* W2 = (const float*)d_in[6];
    const float* b2 = (const float*)d_in[7];
    const float* W3 = (const float*)d_in[8];
    const float* b3 = (const float*)d_in[9];

    const int E = in_sizes[1] / 2;
    const int N = in_sizes[0] / F_DIM;
    const int NNZ = E + N;
    const int NB = (N + SCAN_CHUNK - 1) / SCAN_CHUNK;

    const int* src = edge_index;
    const int* dst = edge_index + E;

    char* ws = (char*)d_ws;
    size_t off = 0;
    auto carve = [&](size_t bytes) -> void* {
        void* p = ws + off;
        off = (off + bytes + 255) & ~(size_t)255;
        return p;
    };
    unsigned short* hbA = (unsigned short*)carve((size_t)N * F_DIM * sizeof(unsigned short));
    unsigned short* hbB = (unsigned short*)carve((size_t)N * F_DIM * sizeof(unsigned short));
    unsigned short* hw3 = (unsigned short*)carve((size_t)N * 40 * sizeof(unsigned short));
    unsigned short* WT0 = (unsigned short*)carve(128 * 128 * sizeof(unsigned short));
    unsigned short* WT1 = (unsigned short*)carve(128 * 128 * sizeof(unsigned short));
    unsigned short* WT2 = (unsigned short*)carve(128 * 128 * sizeof(unsigned short));
    unsigned short* WT3 = (unsigned short*)carve(48 * 128 * sizeof(unsigned short));
    int* count = (int*)carve((size_t)N * sizeof(int));
    float* dinv = (float*)carve((size_t)N * sizeof(float));
    int* rowptr = (int*)carve((size_t)(N + 1) * sizeof(int));
    int* writepos = (int*)carve((size_t)N * sizeof(int));
    int* colbuf = (int*)carve((size_t)NNZ * sizeof(int));
    float* valbuf = (float*)carve((size_t)NNZ * sizeof(float));
    int* blocksum = (int*)carve((size_t)NB * sizeof(int));
    int* blockoff = (int*)carve((size_t)(NB + 1) * sizeof(int));
    (void)ws_size;

    // preprocessing
    hipMemsetAsync(count, 0, (size_t)N * sizeof(int), stream);
    count_dst_kernel<<<(E + 255) / 256, 256, 0, stream>>>(dst, count, E);
    {
        long nChunks = (long)N * F_DIM / 8;
        cvt_bf16_kernel<<<(int)((nChunks + 255) / 256), 256, 0, stream>>>(x, hbA, nChunks);
    }
    cvt_weights_kernel<<<(3 * 16384 + 48 * 128 + 255) / 256, 256, 0, stream>>>(
        W0, W1, W2, W3, WT0, WT1, WT2, WT3);
    scan_partial_kernel<<<NB, SCAN_T, 0, stream>>>(count, blocksum, N);
    scan_sums_kernel<<<1, 1024, 0, stream>>>(blocksum, blockoff, NB);
    scan_write_fused_kernel<<<NB, SCAN_T, 0, stream>>>(count, blockoff, rowptr, writepos,
                                                       dinv, colbuf, valbuf, N, NB);
    fill_edges_kernel<<<(E + 255) / 256, 256, 0, stream>>>(src, dst, writepos, colbuf, valbuf, dinv, E);

    // layers: h0=hbA -> h1=hbB -> h2=hbA -> (h3 in LDS) -> hw3
    int nblk32 = (N + 31) / 32;
    fused_layer_mfma<<<nblk32, 256, 0, stream>>>(rowptr, colbuf, valbuf, hbA, WT0, b0, hbB, N);
    fused_layer_mfma<<<nblk32, 256, 0, stream>>>(rowptr, colbuf, valbuf, hbB, WT1, b1, hbA, N);
    fused_layer_mfma_w3<<<nblk32, 256, 0, stream>>>(rowptr, colbuf, valbuf, hbA, WT2, b2, WT3, hw3, N);

    // final: out = A·hw3 + b3
    gather40_bf16_kernel<<<nblk32, 256, 0, stream>>>(rowptr, colbuf, valbuf, hw3, b3, (float*)d_out, N);
}

// Round 13
// 228.885 us; speedup vs baseline: 1.1251x; 1.1251x over previous
//
#include <hip/hip_runtime.h>
#include <hip/hip_bf16.h>

// ---------------------------------------------------------------------------
// 4-layer GCN forward (PyG gcn_norm: add self-loops, D^-1/2 A D^-1/2)
// h stored bf16. Hidden layers (reassociated): h' = relu((A·h)·W + b),
// fused gather + MFMA (32 nodes/block, 8 thr/node, unroll x2 — R11 config,
// best measured; R6/R12 showed deeper pipelining hurts cache behavior).
// Layer 2 fuses the W3 projection (h3 never hits global memory).
// Final: out = A·hw3 + b3 (bf16 gather, 80B rows).
// Preprocessing: count+cvt fused into one grid-partitioned kernel.
// ---------------------------------------------------------------------------

#define F_DIM 128

#define SCAN_T 256
#define SCAN_I 8
#define SCAN_CHUNK (SCAN_T * SCAN_I)   // 2048 items per block

typedef __attribute__((ext_vector_type(8))) short short8;
typedef __attribute__((ext_vector_type(4))) float f32x4;

__device__ __forceinline__ unsigned short f2bf_rne(float f) {
    unsigned int u = __float_as_uint(f);
    unsigned int r = (u + 0x7fffu + ((u >> 16) & 1u)) >> 16;
    return (unsigned short)r;
}

// ---- fused preproc: count_dst atomics + x->bf16 + weight transposes -------
// grid ranges: [0, EB): count; [EB, EB+XB): cvt x; [EB+XB, +WB): weights
__global__ __launch_bounds__(256) void preproc_kernel(const int* __restrict__ dst,
                                                      int* __restrict__ count, int E,
                                                      const float* __restrict__ x,
                                                      unsigned short* __restrict__ xb,
                                                      long nChunks,
                                                      const float* __restrict__ W0,
                                                      const float* __restrict__ W1,
                                                      const float* __restrict__ W2,
                                                      const float* __restrict__ W3,
                                                      unsigned short* __restrict__ WT0,
                                                      unsigned short* __restrict__ WT1,
                                                      unsigned short* __restrict__ WT2,
                                                      unsigned short* __restrict__ WT3,
                                                      int EB, int XB) {
    int b = blockIdx.x;
    if (b < EB) {
        int e = b * 256 + threadIdx.x;
        if (e < E) atomicAdd(&count[dst[e]], 1);
    } else if (b < EB + XB) {
        long idx = (long)(b - EB) * 256 + threadIdx.x;
        if (idx < nChunks) {
            const float4* in4 = (const float4*)x;
            float4 a = in4[idx * 2];
            float4 c = in4[idx * 2 + 1];
            uint4 o;
            o.x = (unsigned)f2bf_rne(a.x) | ((unsigned)f2bf_rne(a.y) << 16);
            o.y = (unsigned)f2bf_rne(a.z) | ((unsigned)f2bf_rne(a.w) << 16);
            o.z = (unsigned)f2bf_rne(c.x) | ((unsigned)f2bf_rne(c.y) << 16);
            o.w = (unsigned)f2bf_rne(c.z) | ((unsigned)f2bf_rne(c.w) << 16);
            ((uint4*)xb)[idx] = o;
        }
    } else {
        int t = (b - EB - XB) * 256 + threadIdx.x;
        if (t < 3 * 16384) {
            int w = t >> 14, i = t & 16383;
            int k = i >> 7, c = i & 127;
            const float* W = (w == 0) ? W0 : (w == 1) ? W1 : W2;
            unsigned short* WT = (w == 0) ? WT0 : (w == 1) ? WT1 : WT2;
            WT[(size_t)c * 128 + k] = f2bf_rne(W[(size_t)k * 128 + c]);
        } else {
            int i = t - 3 * 16384;
            if (i < 48 * 128) {
                int c = i >> 7, k = i & 127;
                WT3[(size_t)c * 128 + k] = (c < 40) ? f2bf_rne(W3[(size_t)k * 40 + c])
                                                    : (unsigned short)0;
            }
        }
    }
}

// ---- two-level scan of (count[i]+1) ---------------------------------------
__global__ __launch_bounds__(SCAN_T) void scan_partial_kernel(const int* __restrict__ count,
                                                              int* __restrict__ blocksum, int n) {
    int b = blockIdx.x, t = threadIdx.x;
    int base = b * SCAN_CHUNK + t * SCAN_I;
    int s = 0;
#pragma unroll
    for (int j = 0; j < SCAN_I; ++j) {
        int i = base + j;
        if (i < n) s += count[i] + 1;
    }
    __shared__ int red[SCAN_T];
    red[t] = s;
    __syncthreads();
    for (int off = SCAN_T / 2; off > 0; off >>= 1) {
        if (t < off) red[t] += red[t + off];
        __syncthreads();
    }
    if (t == 0) blocksum[b] = red[0];
}

__global__ __launch_bounds__(1024) void scan_sums_kernel(const int* __restrict__ blocksum,
                                                         int* __restrict__ blockoff, int nb) {
    __shared__ int sums[1024];
    int t = threadIdx.x;
    sums[t] = (t < nb) ? blocksum[t] : 0;
    __syncthreads();
    for (int off = 1; off < 1024; off <<= 1) {
        int v = (t >= off) ? sums[t - off] : 0;
        __syncthreads();
        sums[t] += v;
        __syncthreads();
    }
    if (t < nb) blockoff[t] = (t == 0) ? 0 : sums[t - 1];
    if (t == 0) blockoff[nb] = sums[nb - 1];
}

// scan_write + dinv + self-loop fill fused
__global__ __launch_bounds__(SCAN_T) void scan_write_fused_kernel(const int* __restrict__ count,
                                                                  const int* __restrict__ blockoff,
                                                                  int* __restrict__ rowptr,
                                                                  int* __restrict__ writepos,
                                                                  float* __restrict__ dinv,
                                                                  int* __restrict__ col,
                                                                  float* __restrict__ val,
                                                                  int n, int nb) {
    int b = blockIdx.x, t = threadIdx.x;
    int base = b * SCAN_CHUNK + t * SCAN_I;
    int c[SCAN_I];
    int s = 0;
#pragma unroll
    for (int j = 0; j < SCAN_I; ++j) {
        int i = base + j;
        c[j] = (i < n) ? count[i] + 1 : 0;
        s += c[j];
    }
    __shared__ int sums[SCAN_T];
    sums[t] = s;
    __syncthreads();
    for (int off = 1; off < SCAN_T; off <<= 1) {
        int v = (t >= off) ? sums[t - off] : 0;
        __syncthreads();
        sums[t] += v;
        __syncthreads();
    }
    int offset = blockoff[b] + ((t == 0) ? 0 : sums[t - 1]);
#pragma unroll
    for (int j = 0; j < SCAN_I; ++j) {
        int i = base + j;
        if (i < n) {
            rowptr[i] = offset;
            float d = rsqrtf((float)c[j]);
            dinv[i] = d;
            col[offset] = i;
            val[offset] = d * d;
            writepos[i] = offset + 1;
            offset += c[j];
        }
    }
    if (b == 0 && t == 0) rowptr[n] = blockoff[nb];
}

__global__ void fill_edges_kernel(const int* __restrict__ src, const int* __restrict__ dst,
                                  int* __restrict__ writepos, int* __restrict__ col,
                                  float* __restrict__ val, const float* __restrict__ dinv, int E) {
    int e = blockIdx.x * blockDim.x + threadIdx.x;
    if (e < E) {
        int s = src[e], d = dst[e];
        int p = atomicAdd(&writepos[d], 1);
        col[p] = s;
        val[p] = dinv[s] * dinv[d];
    }
}

// unpack-accumulate: acc[0..7] += v * bf16x8(u)
__device__ __forceinline__ void acc8_bf16(float* acc, uint4 u, float v) {
    unsigned w[4] = {u.x, u.y, u.z, u.w};
#pragma unroll
    for (int i = 0; i < 4; ++i) {
        float lo = __uint_as_float(w[i] << 16);
        float hi = __uint_as_float(w[i] & 0xffff0000u);
        acc[2 * i] += v * lo;
        acc[2 * i + 1] += v * hi;
    }
}

// ---- phase-1 gather (R11 config: unroll x2) -------------------------------
__device__ __forceinline__ void gather_phase1(const int* __restrict__ rowptr,
                                              const int* __restrict__ col,
                                              const float* __restrict__ val,
                                              const uint4* __restrict__ H16,
                                              unsigned short (*aggb)[136], int n) {
    int m = threadIdx.x >> 3;
    int p = threadIdx.x & 7;
    int node = blockIdx.x * 32 + m;
    float acc[16];
#pragma unroll
    for (int q = 0; q < 16; ++q) acc[q] = 0.f;
    if (node < n) {
        int s = rowptr[node], e = rowptr[node + 1];
        int j = s;
        for (; j + 1 < e; j += 2) {
            int c0 = col[j], c1 = col[j + 1];
            float v0 = val[j], v1 = val[j + 1];
            const uint4* r0 = H16 + (size_t)c0 * 16 + p;
            const uint4* r1 = H16 + (size_t)c1 * 16 + p;
            uint4 a0 = r0[0], a1 = r0[8];
            uint4 b0 = r1[0], b1 = r1[8];
            acc8_bf16(acc + 0, a0, v0);
            acc8_bf16(acc + 8, a1, v0);
            acc8_bf16(acc + 0, b0, v1);
            acc8_bf16(acc + 8, b1, v1);
        }
        if (j < e) {
            int c0 = col[j];
            float v0 = val[j];
            const uint4* r0 = H16 + (size_t)c0 * 16 + p;
            uint4 a0 = r0[0], a1 = r0[8];
            acc8_bf16(acc + 0, a0, v0);
            acc8_bf16(acc + 8, a1, v0);
        }
    }
    short8 s0, s1;
#pragma unroll
    for (int q = 0; q < 8; ++q) s0[q] = (short)f2bf_rne(acc[q]);
#pragma unroll
    for (int q = 0; q < 8; ++q) s1[q] = (short)f2bf_rne(acc[8 + q]);
    *(short8*)&aggb[m][8 * p] = s0;
    *(short8*)&aggb[m][64 + 8 * p] = s1;
}

// ---- fused hidden layer (bf16 in/out, MFMA phase 2) -----------------------
__global__ __launch_bounds__(256, 8) void fused_layer_mfma(const int* __restrict__ rowptr,
                                                           const int* __restrict__ col,
                                                           const float* __restrict__ val,
                                                           const unsigned short* __restrict__ Hin,
                                                           const unsigned short* __restrict__ WT,
                                                           const float* __restrict__ bias,
                                                           unsigned short* __restrict__ Hout,
                                                           int n) {
    __shared__ unsigned short aggb[32][136];
    gather_phase1(rowptr, col, val, (const uint4*)Hin, aggb, n);
    __syncthreads();

    int lane = threadIdx.x & 63;
    int wv = threadIdx.x >> 6;
    int l15 = lane & 15;
    int lg = lane >> 4;

    f32x4 a00 = {0.f, 0.f, 0.f, 0.f}, a01 = a00, a10 = a00, a11 = a00;

#pragma unroll
    for (int kc = 0; kc < 4; ++kc) {
        int ko = kc * 32 + lg * 8;
        short8 fa0 = *(const short8*)&aggb[l15][ko];
        short8 fa1 = *(const short8*)&aggb[l15 + 16][ko];
        short8 fb0 = *(const short8*)&WT[(size_t)(wv * 32 + l15) * 128 + ko];
        short8 fb1 = *(const short8*)&WT[(size_t)(wv * 32 + 16 + l15) * 128 + ko];
        a00 = __builtin_amdgcn_mfma_f32_16x16x32_bf16(fa0, fb0, a00, 0, 0, 0);
        a01 = __builtin_amdgcn_mfma_f32_16x16x32_bf16(fa0, fb1, a01, 0, 0, 0);
        a10 = __builtin_amdgcn_mfma_f32_16x16x32_bf16(fa1, fb0, a10, 0, 0, 0);
        a11 = __builtin_amdgcn_mfma_f32_16x16x32_bf16(fa1, fb1, a11, 0, 0, 0);
    }

    int base = blockIdx.x * 32;
#pragma unroll
    for (int nt = 0; nt < 2; ++nt) {
        int c = wv * 32 + nt * 16 + l15;
        float bv = bias[c];
#pragma unroll
        for (int mt = 0; mt < 2; ++mt) {
            f32x4 acc = (mt == 0) ? (nt == 0 ? a00 : a01) : (nt == 0 ? a10 : a11);
#pragma unroll
            for (int r = 0; r < 4; ++r) {
                int node = base + mt * 16 + lg * 4 + r;
                if (node < n) {
                    float o = fmaxf(acc[r] + bv, 0.f);
                    Hout[(size_t)node * 128 + c] = f2bf_rne(o);
                }
            }
        }
    }
}

// ---- fused layer 2 + W3 projection ----------------------------------------
__global__ __launch_bounds__(256, 8) void fused_layer_mfma_w3(const int* __restrict__ rowptr,
                                                              const int* __restrict__ col,
                                                              const float* __restrict__ val,
                                                              const unsigned short* __restrict__ Hin,
                                                              const unsigned short* __restrict__ WT,
                                                              const float* __restrict__ bias,
                                                              const unsigned short* __restrict__ WT3,
                                                              unsigned short* __restrict__ hw3,
                                                              int n) {
    __shared__ unsigned short aggb[32][136];
    gather_phase1(rowptr, col, val, (const uint4*)Hin, aggb, n);
    __syncthreads();

    int lane = threadIdx.x & 63;
    int wv = threadIdx.x >> 6;
    int l15 = lane & 15;
    int lg = lane >> 4;

    f32x4 a00 = {0.f, 0.f, 0.f, 0.f}, a01 = a00, a10 = a00, a11 = a00;

#pragma unroll
    for (int kc = 0; kc < 4; ++kc) {
        int ko = kc * 32 + lg * 8;
        short8 fa0 = *(const short8*)&aggb[l15][ko];
        short8 fa1 = *(const short8*)&aggb[l15 + 16][ko];
        short8 fb0 = *(const short8*)&WT[(size_t)(wv * 32 + l15) * 128 + ko];
        short8 fb1 = *(const short8*)&WT[(size_t)(wv * 32 + 16 + l15) * 128 + ko];
        a00 = __builtin_amdgcn_mfma_f32_16x16x32_bf16(fa0, fb0, a00, 0, 0, 0);
        a01 = __builtin_amdgcn_mfma_f32_16x16x32_bf16(fa0, fb1, a01, 0, 0, 0);
        a10 = __builtin_amdgcn_mfma_f32_16x16x32_bf16(fa1, fb0, a10, 0, 0, 0);
        a11 = __builtin_amdgcn_mfma_f32_16x16x32_bf16(fa1, fb1, a11, 0, 0, 0);
    }

    __syncthreads();
#pragma unroll
    for (int nt = 0; nt < 2; ++nt) {
        int c = wv * 32 + nt * 16 + l15;
        float bv = bias[c];
#pragma unroll
        for (int mt = 0; mt < 2; ++mt) {
            f32x4 acc = (mt == 0) ? (nt == 0 ? a00 : a01) : (nt == 0 ? a10 : a11);
#pragma unroll
            for (int r = 0; r < 4; ++r) {
                int row = mt * 16 + lg * 4 + r;
                aggb[row][c] = f2bf_rne(fmaxf(acc[r] + bv, 0.f));
            }
        }
    }
    __syncthreads();

    if (wv < 3) {
        f32x4 c0 = {0.f, 0.f, 0.f, 0.f}, c1 = c0;
#pragma unroll
        for (int kc = 0; kc < 4; ++kc) {
            int ko = kc * 32 + lg * 8;
            short8 fa0 = *(const short8*)&aggb[l15][ko];
            short8 fa1 = *(const short8*)&aggb[l15 + 16][ko];
            short8 fb = *(const short8*)&WT3[(size_t)(wv * 16 + l15) * 128 + ko];
            c0 = __builtin_amdgcn_mfma_f32_16x16x32_bf16(fa0, fb, c0, 0, 0, 0);
            c1 = __builtin_amdgcn_mfma_f32_16x16x32_bf16(fa1, fb, c1, 0, 0, 0);
        }
        int ccol = wv * 16 + l15;
        if (ccol < 40) {
            int base = blockIdx.x * 32;
#pragma unroll
            for (int mt = 0; mt < 2; ++mt) {
                f32x4 acc = (mt == 0) ? c0 : c1;
#pragma unroll
                for (int r = 0; r < 4; ++r) {
                    int node = base + mt * 16 + lg * 4 + r;
                    if (node < n) hw3[(size_t)node * 40 + ccol] = f2bf_rne(acc[r]);
                }
            }
        }
    }
}

// ---- gather40: out[dst] = sum val * hw3_bf16[src] + b3, 40 feats ----------
__global__ __launch_bounds__(256, 8) void gather40_bf16_kernel(const int* __restrict__ rowptr,
                                                               const int* __restrict__ col,
                                                               const float* __restrict__ val,
                                                               const unsigned short* __restrict__ hw3,
                                                               const float* __restrict__ bias,
                                                               float* __restrict__ out, int n) {
    int m = threadIdx.x >> 3;
    int p = threadIdx.x & 7;
    int node = blockIdx.x * 32 + m;
    if (node >= n) return;

    float a0x = 0.f, a0y = 0.f, a0z = 0.f, a0w = 0.f;
    float a1x = 0.f, a1y = 0.f, a1z = 0.f, a1w = 0.f;

    int s = rowptr[node], e = rowptr[node + 1];
    int j = s;
    for (; j + 1 < e; j += 2) {
        int c0 = col[j], c1 = col[j + 1];
        float v0 = val[j], v1 = val[j + 1];
        const uint2* r0 = (const uint2*)(hw3 + (size_t)c0 * 40);
        const uint2* r1 = (const uint2*)(hw3 + (size_t)c1 * 40);
        uint2 u0 = r0[p], u1 = r1[p];
        a0x += v0 * __uint_as_float(u0.x << 16) + v1 * __uint_as_float(u1.x << 16);
        a0y += v0 * __uint_as_float(u0.x & 0xffff0000u) + v1 * __uint_as_float(u1.x & 0xffff0000u);
        a0z += v0 * __uint_as_float(u0.y << 16) + v1 * __uint_as_float(u1.y << 16);
        a0w += v0 * __uint_as_float(u0.y & 0xffff0000u) + v1 * __uint_as_float(u1.y & 0xffff0000u);
        if (p < 2) {
            uint2 w0 = r0[8 + p], w1 = r1[8 + p];
            a1x += v0 * __uint_as_float(w0.x << 16) + v1 * __uint_as_float(w1.x << 16);
            a1y += v0 * __uint_as_float(w0.x & 0xffff0000u) + v1 * __uint_as_float(w1.x & 0xffff0000u);
            a1z += v0 * __uint_as_float(w0.y << 16) + v1 * __uint_as_float(w1.y << 16);
            a1w += v0 * __uint_as_float(w0.y & 0xffff0000u) + v1 * __uint_as_float(w1.y & 0xffff0000u);
        }
    }
    if (j < e) {
        int c0 = col[j];
        float v0 = val[j];
        const uint2* r0 = (const uint2*)(hw3 + (size_t)c0 * 40);
        uint2 u = r0[p];
        a0x += v0 * __uint_as_float(u.x << 16);
        a0y += v0 * __uint_as_float(u.x & 0xffff0000u);
        a0z += v0 * __uint_as_float(u.y << 16);
        a0w += v0 * __uint_as_float(u.y & 0xffff0000u);
        if (p < 2) {
            uint2 w = r0[8 + p];
            a1x += v0 * __uint_as_float(w.x << 16);
            a1y += v0 * __uint_as_float(w.x & 0xffff0000u);
            a1z += v0 * __uint_as_float(w.y << 16);
            a1w += v0 * __uint_as_float(w.y & 0xffff0000u);
        }
    }

    const float4* bi = (const float4*)bias;
    float4 bv = bi[p];
    float4 o0;
    o0.x = a0x + bv.x; o0.y = a0y + bv.y;
    o0.z = a0z + bv.z; o0.w = a0w + bv.w;
    ((float4*)(out + (size_t)node * 40))[p] = o0;
    if (p < 2) {
        float4 bw = bi[8 + p];
        float4 o1;
        o1.x = a1x + bw.x; o1.y = a1y + bw.y;
        o1.z = a1z + bw.z; o1.w = a1w + bw.w;
        ((float4*)(out + (size_t)node * 40))[8 + p] = o1;
    }
}

extern "C" void kernel_launch(void* const* d_in, const int* in_sizes, int n_in,
                              void* d_out, int out_size, void* d_ws, size_t ws_size,
                              hipStream_t stream) {
    const float* x = (const float*)d_in[0];
    const int* edge_index = (const int*)d_in[1];
    const float* W0 = (const float*)d_in[2];
    const float* b0 = (const float*)d_in[3];
    const float* W1 = (const float*)d_in[4];
    const float* b1 = (const float*)d_in[5];
    const float* W2 = (const float*)d_in[6];
    const float* b2 = (const float*)d_in[7];
    const float* W3 = (const float*)d_in[8];
    const float* b3 = (const float*)d_in[9];

    const int E = in_sizes[1] / 2;
    const int N = in_sizes[0] / F_DIM;
    const int NNZ = E + N;
    const int NB = (N + SCAN_CHUNK - 1) / SCAN_CHUNK;

    const int* src = edge_index;
    const int* dst = edge_index + E;

    char* ws = (char*)d_ws;
    size_t off = 0;
    auto carve = [&](size_t bytes) -> void* {
        void* p = ws + off;
        off = (off + bytes + 255) & ~(size_t)255;
        return p;
    };
    unsigned short* hbA = (unsigned short*)carve((size_t)N * F_DIM * sizeof(unsigned short));
    unsigned short* hbB = (unsigned short*)carve((size_t)N * F_DIM * sizeof(unsigned short));
    unsigned short* hw3 = (unsigned short*)carve((size_t)N * 40 * sizeof(unsigned short));
    unsigned short* WT0 = (unsigned short*)carve(128 * 128 * sizeof(unsigned short));
    unsigned short* WT1 = (unsigned short*)carve(128 * 128 * sizeof(unsigned short));
    unsigned short* WT2 = (unsigned short*)carve(128 * 128 * sizeof(unsigned short));
    unsigned short* WT3 = (unsigned short*)carve(48 * 128 * sizeof(unsigned short));
    int* count = (int*)carve((size_t)N * sizeof(int));
    float* dinv = (float*)carve((size_t)N * sizeof(float));
    int* rowptr = (int*)carve((size_t)(N + 1) * sizeof(int));
    int* writepos = (int*)carve((size_t)N * sizeof(int));
    int* colbuf = (int*)carve((size_t)NNZ * sizeof(int));
    float* valbuf = (float*)carve((size_t)NNZ * sizeof(float));
    int* blocksum = (int*)carve((size_t)NB * sizeof(int));
    int* blockoff = (int*)carve((size_t)(NB + 1) * sizeof(int));
    (void)ws_size;

    // preprocessing: memset, then ONE fused kernel (count + cvt x + cvt W)
    hipMemsetAsync(count, 0, (size_t)N * sizeof(int), stream);
    {
        long nChunks = (long)N * F_DIM / 8;
        int EB = (E + 255) / 256;
        int XB = (int)((nChunks + 255) / 256);
        int WB = (3 * 16384 + 48 * 128 + 255) / 256;
        preproc_kernel<<<EB + XB + WB, 256, 0, stream>>>(dst, count, E, x, hbA, nChunks,
                                                         W0, W1, W2, W3, WT0, WT1, WT2, WT3,
                                                         EB, XB);
    }
    scan_partial_kernel<<<NB, SCAN_T, 0, stream>>>(count, blocksum, N);
    scan_sums_kernel<<<1, 1024, 0, stream>>>(blocksum, blockoff, NB);
    scan_write_fused_kernel<<<NB, SCAN_T, 0, stream>>>(count, blockoff, rowptr, writepos,
                                                       dinv, colbuf, valbuf, N, NB);
    fill_edges_kernel<<<(E + 255) / 256, 256, 0, stream>>>(src, dst, writepos, colbuf, valbuf, dinv, E);

    // layers: h0=hbA -> h1=hbB -> h2=hbA -> (h3 in LDS) -> hw3
    int nblk32 = (N + 31) / 32;
    fused_layer_mfma<<<nblk32, 256, 0, stream>>>(rowptr, colbuf, valbuf, hbA, WT0, b0, hbB, N);
    fused_layer_mfma<<<nblk32, 256, 0, stream>>>(rowptr, colbuf, valbuf, hbB, WT1, b1, hbA, N);
    fused_layer_mfma_w3<<<nblk32, 256, 0, stream>>>(rowptr, colbuf, valbuf, hbA, WT2, b2, WT3, hw3, N);

    // final: out = A·hw3 + b3
    gather40_bf16_kernel<<<nblk32, 256, 0, stream>>>(rowptr, colbuf, valbuf, hw3, b3, (float*)d_out, N);
}